// Round 11
// baseline (283.192 us; speedup 1.0000x reference)
//
#include <hip/hip_runtime.h>
#include <math.h>

#define D 128

typedef __attribute__((ext_vector_type(8))) short short8v;   // 8 bf16 (4 VGPR)
typedef __attribute__((ext_vector_type(4))) float f32x4;      // MFMA acc
typedef __attribute__((ext_vector_type(4))) unsigned int uint4v;

// fast swish: a*x*sigmoid(b*x), exp2+rcp form (~6 VALU insts, rel err <2^-21)
__device__ __forceinline__ float fast_swish(float v, float a, float b) {
  float e = __builtin_amdgcn_exp2f(-1.4426950408889634f * (b * v));
  return a * v * __builtin_amdgcn_rcpf(1.0f + e);
}

// exact RNE split (prep only): v ~= hi + lo, err ~2^-18
__device__ __forceinline__ void bf16split_rne(float v, unsigned short& h, unsigned short& l) {
  unsigned int u = __float_as_uint(v);
  unsigned int rh = (u + 0x7FFFu + ((u >> 16) & 1u)) & 0xFFFF0000u;
  h = (unsigned short)(rh >> 16);
  float lf = v - __uint_as_float(rh);
  unsigned int u2 = __float_as_uint(lf);
  unsigned int rl = u2 + 0x7FFFu + ((u2 >> 16) & 1u);
  l = (unsigned short)(rl >> 16);
}

// fast split (hot path): truncate hi, RNE lo; reconstruction err ~2^-17
__device__ __forceinline__ void bf16split_fast(float v, unsigned short& h, unsigned short& l) {
  unsigned int u = __float_as_uint(v);
  h = (unsigned short)(u >> 16);
  float lf = v - __uint_as_float(u & 0xFFFF0000u);
  unsigned int u2 = __float_as_uint(lf);
  l = (unsigned short)((u2 + 0x7FFFu + ((u2 >> 16) & 1u)) >> 16);
}

// bf16x2-split 16x16x32 step: 3 MFMAs
__device__ __forceinline__ f32x4 mfma3(short8v ah, short8v al, short8v bh, short8v bl, f32x4 acc) {
  acc = __builtin_amdgcn_mfma_f32_16x16x32_bf16(al, bh, acc, 0, 0, 0);
  acc = __builtin_amdgcn_mfma_f32_16x16x32_bf16(ah, bl, acc, 0, 0, 0);
  acc = __builtin_amdgcn_mfma_f32_16x16x32_bf16(ah, bh, acc, 0, 0, 0);
  return acc;
}

// ---- stage a 16x128 f32 tile into XOR-swizzled hi/lo bf16 LDS (1 wave) ----
template <bool SW>
__device__ __forceinline__ void stage16(const float* __restrict__ src, int lane,
                                        unsigned short* shHi, unsigned short* shLo,
                                        float a, float b) {
#pragma unroll
  for (int i = 0; i < 4; ++i) {
    int t = lane + 64 * i;
    int r = t >> 4, c = t & 15;          // row, 8-float chunk
    const float4 v0 = *(const float4*)(src + r * D + c * 8);
    const float4 v1 = *(const float4*)(src + r * D + c * 8 + 4);
    float vv[8] = {v0.x, v0.y, v0.z, v0.w, v1.x, v1.y, v1.z, v1.w};
    unsigned int hw[4], lw[4];
#pragma unroll
    for (int jj = 0; jj < 4; ++jj) {
      float x0 = SW ? fast_swish(vv[2 * jj], a, b) : vv[2 * jj];
      float x1 = SW ? fast_swish(vv[2 * jj + 1], a, b) : vv[2 * jj + 1];
      unsigned short h0, l0, h1, l1;
      bf16split_fast(x0, h0, l0);
      bf16split_fast(x1, h1, l1);
      hw[jj] = (unsigned int)h0 | ((unsigned int)h1 << 16);
      lw[jj] = (unsigned int)l0 | ((unsigned int)l1 << 16);
    }
    int off = (c * 16) ^ ((r & 7) << 4);
    uint4v hv = {hw[0], hw[1], hw[2], hw[3]};
    uint4v lv = {lw[0], lw[1], lw[2], lw[3]};
    *(uint4v*)((char*)(shHi + r * D) + off) = hv;
    *(uint4v*)((char*)(shLo + r * D) + off) = lv;
  }
}

// ---- prep: 19 [128x128] f32 matrices -> fragment-major bf16 hi/lo planes ----
__global__ void prep_weights_kernel(const float* __restrict__ W1, const float* __restrict__ W2,
                                    const float* __restrict__ Wo, const float* __restrict__ P1,
                                    const float* __restrict__ P2, const float* __restrict__ D1,
                                    const float* __restrict__ D2, unsigned short* __restrict__ prep) {
  int t = blockIdx.x * 256 + threadIdx.x;
  if (t >= 19 * 2048) return;
  int m = t >> 11;
  int rem = t & 2047;
  int nt = rem >> 8;
  int kc = (rem >> 6) & 3;
  int lane = rem & 63;
  const float* src;
  if (m < 5) src = W1 + (size_t)m * 16384;
  else if (m < 10) src = W2 + (size_t)(m - 5) * 16384;
  else if (m < 15) src = Wo + (size_t)(m - 10) * 16384;
  else if (m == 15) src = P1;
  else if (m == 16) src = P2;
  else if (m == 17) src = D1;
  else src = D2;
  int row = nt * 16 + (lane & 15);            // N index
  int k0 = kc * 32 + (lane >> 4) * 8;         // K index
  unsigned int hw[4], lw[4];
#pragma unroll
  for (int jj = 0; jj < 4; ++jj) {
    unsigned short h0, l0, h1, l1;
    bf16split_rne(src[row * D + k0 + 2 * jj], h0, l0);
    bf16split_rne(src[row * D + k0 + 2 * jj + 1], h1, l1);
    hw[jj] = (unsigned int)h0 | ((unsigned int)h1 << 16);
    lw[jj] = (unsigned int)l0 | ((unsigned int)l1 << 16);
  }
  size_t chunk = (size_t)((nt * 4 + kc) * 64 + lane);
  uint4v hv = {hw[0], hw[1], hw[2], hw[3]};
  uint4v lv = {lw[0], lw[1], lw[2], lw[3]};
  *(uint4v*)(prep + (size_t)(2 * m) * 16384 + chunk * 8) = hv;
  *(uint4v*)(prep + (size_t)(2 * m + 1) * 16384 + chunk * 8) = lv;
}

// ---------------- resMLP via MFMA: 64-atom block tile, N split across 4 waves ----
// Branch y==0 writes rows to outA (stride D): c_term -> inp  /  branch 4 -> d_out.
// Branches y=1..3 write interleaved featsI[atom][y-1][D] (stride 3D) for the
// aggregate gather (one contiguous 1536B read per edge).
__global__ __launch_bounds__(256) void resmlp_mfma(
    const float* __restrict__ xin, const unsigned short* __restrict__ prep,
    const float* __restrict__ b1b, const float* __restrict__ b2b,
    const float* __restrict__ act_a, const float* __restrict__ act_b,
    float* __restrict__ outA, float* __restrict__ outB,
    int branch_off, int n_atoms)
{
  __shared__ __align__(16) unsigned short shHi[64 * D];
  __shared__ __align__(16) unsigned short shLo[64 * D];
  const int lane = threadIdx.x & 63;
  const int wid = threadIdx.x >> 6;
  const int atom0 = blockIdx.x * 64;
  const int y = blockIdx.y;
  const int br = y + branch_off;
  const float* b1 = b1b + br * D;
  const float* b2 = b2b + br * D;
  const float a0 = act_a[br * 3 + 0], g0 = act_b[br * 3 + 0];
  const float a1 = act_a[br * 3 + 1], g1 = act_b[br * 3 + 1];
  const float a2 = act_a[br * 3 + 2], g2 = act_b[br * 3 + 2];
  const float* x0 = xin + (size_t)atom0 * D;

  // cooperative stage: wave w stages rows [16w,16w+16) with swish applied
  stage16<true>(x0 + wid * 16 * D, lane, shHi + wid * 16 * D, shLo + wid * 16 * D, a0, g0);
  __syncthreads();

  const int rl = lane & 15;
  const int q = lane >> 4;
  const int rowq = q * 4;
  const int nt0 = wid * 2;

  f32x4 acc[4][2];

#define GEMM_LAYER(mat)                                                        \
  do {                                                                         \
    const unsigned short* ph = prep + (size_t)(2 * (mat)) * 16384;             \
    const unsigned short* pl = prep + (size_t)(2 * (mat) + 1) * 16384;         \
    _Pragma("unroll") for (int mt = 0; mt < 4; ++mt)                           \
        _Pragma("unroll") for (int j = 0; j < 2; ++j)                          \
            acc[mt][j] = f32x4{0.f, 0.f, 0.f, 0.f};                            \
    _Pragma("unroll") for (int kc = 0; kc < 4; ++kc) {                         \
      int ci0 = (nt0 * 4 + kc) * 64 + lane;                                    \
      int ci1 = ((nt0 + 1) * 4 + kc) * 64 + lane;                              \
      short8v bh0 = *(const short8v*)(ph + (size_t)ci0 * 8);                   \
      short8v bl0 = *(const short8v*)(pl + (size_t)ci0 * 8);                   \
      short8v bh1 = *(const short8v*)(ph + (size_t)ci1 * 8);                   \
      short8v bl1 = *(const short8v*)(pl + (size_t)ci1 * 8);                   \
      int aoff = (kc * 64 + q * 16) ^ ((rl & 7) << 4);                         \
      _Pragma("unroll") for (int mt = 0; mt < 4; ++mt) {                       \
        short8v ah = *(const short8v*)((const char*)(shHi + (mt * 16 + rl) * D) + aoff); \
        short8v al = *(const short8v*)((const char*)(shLo + (mt * 16 + rl) * D) + aoff); \
        acc[mt][0] = mfma3(ah, al, bh0, bl0, acc[mt][0]);                      \
        acc[mt][1] = mfma3(ah, al, bh1, bl1, acc[mt][1]);                      \
      }                                                                        \
    }                                                                          \
  } while (0)

  // layer 1: h = s0 @ W1^T + b1; s1 = swish(h)
  GEMM_LAYER(br);
  __syncthreads();   // all reads of s0 done before overwrite
#pragma unroll
  for (int j = 0; j < 2; ++j) {
    int col = (nt0 + j) * 16 + rl;
    float bv = b1[col];
#pragma unroll
    for (int mt = 0; mt < 4; ++mt)
#pragma unroll
      for (int r = 0; r < 4; ++r) {
        int row = mt * 16 + rowq + r;
        float s = fast_swish(acc[mt][j][r] + bv, a1, g1);
        unsigned short h, l;
        bf16split_fast(s, h, l);
        int off = (col * 2) ^ ((row & 7) << 4);
        *(unsigned short*)((char*)(shHi + row * D) + off) = h;
        *(unsigned short*)((char*)(shLo + row * D) + off) = l;
      }
  }
  __syncthreads();

  // layer 2: y = x0 + s1 @ W2^T + b2; s2 = swish(y)
  GEMM_LAYER(5 + br);
  __syncthreads();
#pragma unroll
  for (int j = 0; j < 2; ++j) {
    int col = (nt0 + j) * 16 + rl;
    float bv = b2[col];
#pragma unroll
    for (int mt = 0; mt < 4; ++mt)
#pragma unroll
      for (int r = 0; r < 4; ++r) {
        int row = mt * 16 + rowq + r;
        float yv = x0[row * D + col] + acc[mt][j][r] + bv;   // residual (L1/L2 re-read)
        float s = fast_swish(yv, a2, g2);
        unsigned short h, l;
        bf16split_fast(s, h, l);
        int off = (col * 2) ^ ((row & 7) << 4);
        *(unsigned short*)((char*)(shHi + row * D) + off) = h;
        *(unsigned short*)((char*)(shLo + row * D) + off) = l;
      }
  }
  __syncthreads();

  // layer 3: out = s2 @ Wo^T
  GEMM_LAYER(10 + br);
#pragma unroll
  for (int mt = 0; mt < 4; ++mt)
#pragma unroll
    for (int r = 0; r < 4; ++r) {
      int row = atom0 + mt * 16 + rowq + r;
      float* op = (y == 0) ? (outA + (size_t)row * D)
                           : (outB + ((size_t)row * 3 + (y - 1)) * D);
#pragma unroll
      for (int j = 0; j < 2; ++j)
        op[(nt0 + j) * 16 + rl] = acc[mt][j][r];
    }
#undef GEMM_LAYER
}

// ---------------- take_inner via MFMA: 64-atom tile; eacc atomically into inp ----
__global__ __launch_bounds__(256) void inner_mfma(
    const float* __restrict__ q1, const float* __restrict__ q2,
    const unsigned short* __restrict__ prep,
    float* __restrict__ inp, int n_atoms)
{
  __shared__ __align__(16) unsigned short shHi[64 * D];
  __shared__ __align__(16) unsigned short shLo[64 * D];
  const int lane = threadIdx.x & 63;
  const int wid = threadIdx.x >> 6;
  const int atom0 = blockIdx.x * 64;
  const int g = blockIdx.y;
  const size_t nd = (size_t)n_atoms * D;
  const int rl = lane & 15;
  const int q = lane >> 4;
  const int rowq = q * 4;
  const int nt0 = wid * 2;

  f32x4 eacc[4][2];
#pragma unroll
  for (int mt = 0; mt < 4; ++mt)
#pragma unroll
    for (int j = 0; j < 2; ++j) eacc[mt][j] = f32x4{0.f, 0.f, 0.f, 0.f};

  for (int pp = 0; pp < 2; ++pp) {
    const int part = g * 2 + pp;
    const float* qp = (part < 3) ? q1 + (size_t)part * nd : q2 + (size_t)(part - 3) * nd;
    const int m1 = (part < 3) ? 15 : 17;     // P1/P2 or D1/D2
    if (pp) __syncthreads();                 // prior part's reads done before restage
    stage16<false>(qp + (size_t)atom0 * D + wid * 16 * D, lane,
                   shHi + wid * 16 * D, shLo + wid * 16 * D, 0.f, 0.f);
    __syncthreads();
    const unsigned short* p1h = prep + (size_t)(2 * m1) * 16384;
    const unsigned short* p1l = prep + (size_t)(2 * m1 + 1) * 16384;
    const unsigned short* p2h = prep + (size_t)(2 * m1 + 2) * 16384;
    const unsigned short* p2l = prep + (size_t)(2 * m1 + 3) * 16384;
#pragma unroll
    for (int j = 0; j < 2; ++j) {
      f32x4 t1[4], t2[4];
#pragma unroll
      for (int mt = 0; mt < 4; ++mt) {
        t1[mt] = f32x4{0.f, 0.f, 0.f, 0.f};
        t2[mt] = f32x4{0.f, 0.f, 0.f, 0.f};
      }
#pragma unroll
      for (int kc = 0; kc < 4; ++kc) {
        int ci = ((nt0 + j) * 4 + kc) * 64 + lane;
        short8v b1h = *(const short8v*)(p1h + (size_t)ci * 8);
        short8v b1l = *(const short8v*)(p1l + (size_t)ci * 8);
        short8v b2h = *(const short8v*)(p2h + (size_t)ci * 8);
        short8v b2l = *(const short8v*)(p2l + (size_t)ci * 8);
        int aoff = (kc * 64 + q * 16) ^ ((rl & 7) << 4);
#pragma unroll
        for (int mt = 0; mt < 4; ++mt) {
          short8v ah = *(const short8v*)((const char*)(shHi + (mt * 16 + rl) * D) + aoff);
          short8v al = *(const short8v*)((const char*)(shLo + (mt * 16 + rl) * D) + aoff);
          t1[mt] = mfma3(ah, al, b1h, b1l, t1[mt]);
          t2[mt] = mfma3(ah, al, b2h, b2l, t2[mt]);
        }
      }
#pragma unroll
      for (int mt = 0; mt < 4; ++mt) eacc[mt][j] += t1[mt] * t2[mt];
    }
  }

#pragma unroll
  for (int j = 0; j < 2; ++j)
#pragma unroll
    for (int mt = 0; mt < 4; ++mt)
#pragma unroll
      for (int r = 0; r < 4; ++r)
        atomicAdd(&inp[(size_t)(atom0 + mt * 16 + rowq + r) * D + (nt0 + j) * 16 + rl],
                  eacc[mt][j][r]);
}

// ---------------- CSR build: histogram, scan ----------------
__global__ void hist_kernel(const int* __restrict__ nbrs, int* __restrict__ counts, int n_edges) {
  int e = blockIdx.x * 256 + threadIdx.x;
  if (e < n_edges) atomicAdd(&counts[nbrs[2 * e]], 1);
}

__global__ __launch_bounds__(1024) void scan_kernel(const int* __restrict__ counts,
                                                    int* __restrict__ offsets, int n) {
  __shared__ int part[1024];
  int tid = threadIdx.x;
  int base = tid * 16;
  int loc[16]; int s = 0;
#pragma unroll
  for (int i = 0; i < 16; ++i) {
    int c = (base + i < n) ? counts[base + i] : 0;
    loc[i] = c; s += c;
  }
  part[tid] = s;
  __syncthreads();
  for (int off = 1; off < 1024; off <<= 1) {
    int v = (tid >= off) ? part[tid - off] : 0;
    __syncthreads();
    part[tid] += v;
    __syncthreads();
  }
  int run = (tid == 0) ? 0 : part[tid - 1];
#pragma unroll
  for (int i = 0; i < 16; ++i) {
    if (base + i < n) offsets[base + i] = run;
    run += loc[i];
  }
}

// ---------------- fused scatter + geometry: write rho/y/dst in CSR-sorted order ----
__global__ void scatter_geom_kernel(const float* __restrict__ xyz,
                                    const int* __restrict__ nbrs,
                                    const float* __restrict__ gamma_p,
                                    const int* __restrict__ offsets,
                                    int* __restrict__ cursor,
                                    float* __restrict__ rho_s, float* __restrict__ y_s,
                                    int* __restrict__ dst_s, int n_edges)
{
  int e = blockIdx.x * 256 + threadIdx.x;
  if (e >= n_edges) return;
  int s = nbrs[2 * e], dd = nbrs[2 * e + 1];
  int pos = offsets[s] + atomicAdd(&cursor[s], 1);
  float rx = xyz[3 * dd + 0] - xyz[3 * s + 0];
  float ry = xyz[3 * dd + 1] - xyz[3 * s + 1];
  float rz = xyz[3 * dd + 2] - xyz[3 * s + 2];
  float r2 = rx * rx + ry * ry + rz * rz + 3e-15f;
  float r = sqrtf(r2);
  float inv = 1.0f / r;
  float ux = rx * inv, uy = ry * inv, uz = rz * inv;
  float gamma = gamma_p[0];
  float xv = __expf(-gamma * r);
  float omx = 1.0f - xv;
  float fcut = 0.0f;
  if (r < 5.0f) fcut = __expf(-r2 / (25.0f - r2));
  float xp[16], op[16];
  xp[0] = 1.f; op[0] = 1.f;
#pragma unroll
  for (int k = 1; k < 16; ++k) { xp[k] = xp[k - 1] * xv; op[k] = op[k - 1] * omx; }
  const float C[16] = {1.f, 15.f, 105.f, 455.f, 1365.f, 3003.f, 5005.f, 6435.f,
                       6435.f, 5005.f, 3003.f, 1365.f, 455.f, 105.f, 15.f, 1.f};
  float* rp = rho_s + (size_t)pos * 16;
#pragma unroll
  for (int c4 = 0; c4 < 4; ++c4) {
    float4 v = make_float4(C[4 * c4] * xp[4 * c4] * op[15 - 4 * c4] * fcut,
                           C[4 * c4 + 1] * xp[4 * c4 + 1] * op[14 - 4 * c4] * fcut,
                           C[4 * c4 + 2] * xp[4 * c4 + 2] * op[13 - 4 * c4] * fcut,
                           C[4 * c4 + 3] * xp[4 * c4 + 3] * op[12 - 4 * c4] * fcut);
    *(float4*)(rp + 4 * c4) = v;
  }
  const float s3 = 1.7320508075688772f;
  float* yp = y_s + (size_t)pos * 8;
  *(float4*)yp = make_float4(uy, uz, ux, s3 * ux * uy);
  *(float4*)(yp + 4) = make_float4(s3 * uy * uz, 0.5f * (3.f * uz * uz - 1.f),
                                   s3 * ux * uz, 0.5f * s3 * (ux * ux - uy * uy));
  dst_s[pos] = dd;
}

// ---------------- per-atom aggregation: sequential CSR records + 1536B joint gather ----
// inp[n,d] += q0 contribution (c_term already resident); q1/q2 written m-major.
__global__ __launch_bounds__(128) void aggregate_kernel(
    const float* __restrict__ rho_s, const float* __restrict__ y_s,
    const int* __restrict__ dst_s,
    const int* __restrict__ offsets, const int* __restrict__ counts,
    const float* __restrict__ featsI,
    const float* __restrict__ Gs, const float* __restrict__ Gp,
    const float* __restrict__ Gd,
    float* __restrict__ inp, float* __restrict__ q1, float* __restrict__ q2,
    int n_atoms)
{
  int n = blockIdx.x;
  int d = threadIdx.x;
  float gs[16], gp[16], gd[16];
#pragma unroll
  for (int c = 0; c < 4; ++c) {
    float4 v = *(const float4*)&Gs[d * 16 + 4 * c];
    gs[4 * c] = v.x; gs[4 * c + 1] = v.y; gs[4 * c + 2] = v.z; gs[4 * c + 3] = v.w;
    v = *(const float4*)&Gp[d * 16 + 4 * c];
    gp[4 * c] = v.x; gp[4 * c + 1] = v.y; gp[4 * c + 2] = v.z; gp[4 * c + 3] = v.w;
    v = *(const float4*)&Gd[d * 16 + 4 * c];
    gd[4 * c] = v.x; gd[4 * c + 1] = v.y; gd[4 * c + 2] = v.z; gd[4 * c + 3] = v.w;
  }
  float a0 = 0.f, a1[3] = {0.f, 0.f, 0.f}, a2[5] = {0.f, 0.f, 0.f, 0.f, 0.f};
  const int off = offsets[n], cnt = counts[n];

#define EDGE_BODY(REC)                                                         \
  do {                                                                         \
    const int rec = (REC);                                                     \
    const int dst = dst_s[rec];                                                \
    const float* fb = featsI + (size_t)dst * 384;                              \
    float f1 = fb[d], f2 = fb[128 + d], f3 = fb[256 + d];                      \
    const float4* rp = (const float4*)(rho_s + (size_t)rec * 16);              \
    float4 r0v = rp[0], r1v = rp[1], r2v = rp[2], r3v = rp[3];                 \
    float rho[16] = {r0v.x, r0v.y, r0v.z, r0v.w, r1v.x, r1v.y, r1v.z, r1v.w,   \
                     r2v.x, r2v.y, r2v.z, r2v.w, r3v.x, r3v.y, r3v.z, r3v.w};  \
    const float4* ypv = (const float4*)(y_s + (size_t)rec * 8);                \
    float4 y0v = ypv[0], y1v = ypv[1];                                         \
    float g_s = 0.f, g_p = 0.f, g_d = 0.f;                                     \
    _Pragma("unroll") for (int k = 0; k < 16; ++k) {                           \
      g_s += gs[k] * rho[k];                                                   \
      g_p += gp[k] * rho[k];                                                   \
      g_d += gd[k] * rho[k];                                                   \
    }                                                                          \
    a0 += f1 * g_s;                                                            \
    float ap = f2 * g_p;                                                       \
    a1[0] += ap * y0v.x; a1[1] += ap * y0v.y; a1[2] += ap * y0v.z;             \
    float ad = f3 * g_d;                                                       \
    a2[0] += ad * y0v.w; a2[1] += ad * y1v.x; a2[2] += ad * y1v.y;             \
    a2[3] += ad * y1v.z; a2[4] += ad * y1v.w;                                  \
  } while (0)

  int i = 0;
  for (; i + 2 <= cnt; i += 2) {
    EDGE_BODY(off + i);
    EDGE_BODY(off + i + 1);
  }
  if (i < cnt) EDGE_BODY(off + i);
#undef EDGE_BODY

  size_t idx = (size_t)n * D + d;
  inp[idx] = inp[idx] + a0;       // c_term already there; unique (n,d) -> plain RMW
#pragma unroll
  for (int m = 0; m < 3; ++m) q1[((size_t)m * n_atoms + n) * D + d] = a1[m];
#pragma unroll
  for (int m = 0; m < 5; ++m) q2[((size_t)m * n_atoms + n) * D + d] = a2[m];
}

extern "C" void kernel_launch(void* const* d_in, const int* in_sizes, int n_in,
                              void* d_out, int out_size, void* d_ws, size_t ws_size,
                              hipStream_t stream)
{
  const float* xyz     = (const float*)d_in[0];
  const float* x_tilde = (const float*)d_in[1];
  const int*   nbrs    = (const int*)d_in[2];
  const float* W1      = (const float*)d_in[3];
  const float* b1      = (const float*)d_in[4];
  const float* W2      = (const float*)d_in[5];
  const float* b2      = (const float*)d_in[6];
  const float* Wout    = (const float*)d_in[7];
  const float* act_a   = (const float*)d_in[8];
  const float* act_b   = (const float*)d_in[9];
  const float* Gs      = (const float*)d_in[10];
  const float* Gp      = (const float*)d_in[11];
  const float* Gd      = (const float*)d_in[12];
  const float* P1      = (const float*)d_in[13];
  const float* P2      = (const float*)d_in[14];
  const float* D1m     = (const float*)d_in[15];
  const float* D2m     = (const float*)d_in[16];
  const float* gamma   = (const float*)d_in[17];
  float* out = (float*)d_out;

  const int n_atoms = in_sizes[0] / 3;   // 16384
  const int n_edges = in_sizes[2] / 2;   // 100000

  // workspace layout (floats)
  float* ws = (float*)d_ws;
  size_t nd = (size_t)n_atoms * D;
  float* featsI = ws;                         // 3*nd: interleaved [atom][3][D]
  float* q1     = featsI + 3 * nd;            // 3*nd
  float* q2     = q1 + 3 * nd;                // 5*nd
  float* inp    = q2 + 5 * nd;                // nd (c_term + q0 + inner terms)
  float* rho_s  = inp + nd;                   // E*16 (CSR-sorted)
  float* y_s    = rho_s + (size_t)n_edges * 16;  // E*8
  int* dst_s   = (int*)(y_s + (size_t)n_edges * 8);  // E
  int* counts  = dst_s + n_edges;
  int* offsets = counts + n_atoms;
  int* cursor  = offsets + n_atoms;
  unsigned short* prep =
      (unsigned short*)(((uintptr_t)(cursor + n_atoms) + 15) & ~(uintptr_t)15);

  // zero counts/offsets/cursor in one shot (scan rewrites offsets anyway)
  hipMemsetAsync(counts, 0, (size_t)3 * n_atoms * sizeof(int), stream);

  dim3 blk(256);
  int eb = (n_edges + 255) / 256;

  prep_weights_kernel<<<(19 * 2048 + 255) / 256, blk, 0, stream>>>(
      W1, W2, Wout, P1, P2, D1m, D2m, prep);

  // branches 0..3 on x_tilde: branch0 -> inp (c_term), 1..3 -> featsI interleaved
  resmlp_mfma<<<dim3(n_atoms / 64, 4), dim3(256), 0, stream>>>(
      x_tilde, prep, b1, b2, act_a, act_b, inp, featsI, 0, n_atoms);

  hist_kernel<<<eb, blk, 0, stream>>>(nbrs, counts, n_edges);
  scan_kernel<<<1, 1024, 0, stream>>>(counts, offsets, n_atoms);
  scatter_geom_kernel<<<eb, blk, 0, stream>>>(
      xyz, nbrs, gamma, offsets, cursor, rho_s, y_s, dst_s, n_edges);

  aggregate_kernel<<<n_atoms, 128, 0, stream>>>(
      rho_s, y_s, dst_s, offsets, counts, featsI, Gs, Gp, Gd,
      inp, q1, q2, n_atoms);

  // take_inner split over 4 part-groups; eacc atomically accumulated into inp
  inner_mfma<<<dim3(n_atoms / 64, 4), dim3(256), 0, stream>>>(
      q1, q2, prep, inp, n_atoms);

  // branch 4 on inp -> out
  resmlp_mfma<<<dim3(n_atoms / 64, 1), dim3(256), 0, stream>>>(
      inp, prep, b1, b2, act_a, act_b, out, nullptr, 4, n_atoms);
}